// Round 8
// baseline (197.917 us; speedup 1.0000x reference)
//
#include <hip/hip_runtime.h>
#include <stdint.h>

#define NROWS 4096
#define DIM   512
#define EPS_COS 1e-8f
#define EPS_W   1e-6f
#define NSTEP (DIM / 32)           // 16 K-steps of 32

typedef unsigned short ushort_t;
typedef __attribute__((ext_vector_type(8))) short   short8;
typedef __attribute__((ext_vector_type(8))) unsigned short ushort8;
typedef __attribute__((ext_vector_type(4))) float   floatx4;

// ---------- helpers ----------
__device__ inline ushort_t f2bf(float x) {            // RNE float->bf16
    unsigned u = __float_as_uint(x);
    unsigned r = (u + 0x7FFFu + ((u >> 16) & 1u)) >> 16;
    return (ushort_t)r;
}
__device__ inline float bf2f(ushort_t u) {
    return __uint_as_float(((unsigned)u) << 16);
}
// monotone float<->uint mapping for atomicMin/Max on floats
__device__ inline unsigned fmap(float f) {
    unsigned u = __float_as_uint(f);
    return (u & 0x80000000u) ? ~u : (u | 0x80000000u);
}
__device__ inline float funmap(unsigned u) {
    return __uint_as_float((u & 0x80000000u) ? (u & 0x7fffffffu) : ~u);
}

// Block geometry: 256 thr = 4 waves, each wave owns a 64x64 output tile;
// block output = 64 rows x 256 cols (4 waves side-by-side in n, sharing A rows
// -> L1 serves A-frags 4x). grid = 64 (bi) x 16 (bj) = 1024 blocks.
// XCD map: xcd = bid&7 owns i-slice bi = xcd*8..xcd*8+7 (A slice 0.5 MB,
// L2-resident); within XCD, bi-fast order -> B-tile (256 cols, 256 KB)
// reused by 8 consecutive blocks.
__device__ __forceinline__ void tile_map(int bid, int& bi, int& bj) {
    int xcd = bid & 7, w = bid >> 3;   // w in 0..127
    bi = xcd * 8 + (w & 7);            // 0..63
    bj = w >> 3;                       // 0..15
}

// MFMA fragment load DIRECT from global (byte-identical to the staged path's
// read_frag): lane l -> matrix row (l&15), k = t*32 + (l>>4)*8 .. +7.
// One 16B dwordx4 per lane; lanes {r, r+16, r+32, r+48} cover one 64B line
// -> each frag load = 16 sectored 64B lines, L1/L2-friendly.

// ---------- kernel 1: convert + norms + init ----------
__global__ __launch_bounds__(256) void prep_kernel(
    const float* __restrict__ img, const float* __restrict__ txt,
    ushort_t* __restrict__ Ibf, ushort_t* __restrict__ Tbf,
    float* __restrict__ img_norm, float* __restrict__ txt_norm,
    unsigned* __restrict__ mn_u, unsigned* __restrict__ mx_u) {
    const int wave = threadIdx.x >> 6, lane = threadIdx.x & 63;
    const int row = blockIdx.x * 4 + wave;
    const int col0 = lane * 8;
    {
        const float4* p = reinterpret_cast<const float4*>(img + (size_t)row * DIM + col0);
        float4 a = p[0], b = p[1];
        float ss = a.x*a.x + a.y*a.y + a.z*a.z + a.w*a.w
                 + b.x*b.x + b.y*b.y + b.z*b.z + b.w*b.w;
        ushort8 o;
        o[0]=f2bf(a.x); o[1]=f2bf(a.y); o[2]=f2bf(a.z); o[3]=f2bf(a.w);
        o[4]=f2bf(b.x); o[5]=f2bf(b.y); o[6]=f2bf(b.z); o[7]=f2bf(b.w);
        *reinterpret_cast<ushort8*>(Ibf + (size_t)row * DIM + col0) = o;
#pragma unroll
        for (int s = 1; s < 64; s <<= 1) ss += __shfl_xor(ss, s);
        if (lane == 0) img_norm[row] = sqrtf(ss);
    }
    {
        const float4* p = reinterpret_cast<const float4*>(txt + (size_t)row * DIM + col0);
        float4 a = p[0], b = p[1];
        float ss = a.x*a.x + a.y*a.y + a.z*a.z + a.w*a.w
                 + b.x*b.x + b.y*b.y + b.z*b.z + b.w*b.w;
        ushort8 o;
        o[0]=f2bf(a.x); o[1]=f2bf(a.y); o[2]=f2bf(a.z); o[3]=f2bf(a.w);
        o[4]=f2bf(b.x); o[5]=f2bf(b.y); o[6]=f2bf(b.z); o[7]=f2bf(b.w);
        *reinterpret_cast<ushort8*>(Tbf + (size_t)row * DIM + col0) = o;
#pragma unroll
        for (int s = 1; s < 64; s <<= 1) ss += __shfl_xor(ss, s);
        if (lane == 0) txt_norm[row] = sqrtf(ss);
    }
    if (lane == 0) { mn_u[row] = 0xFFFFFFFFu; mx_u[row] = 0u; }
}

// ---------- kernel 2: S = T.T^T, LDS-free -> minmax atomics + packed bf16 sim ----------
__global__ __launch_bounds__(256, 4) void phase1_kernel(
    const ushort_t* __restrict__ Tbf,
    unsigned* __restrict__ mn_u, unsigned* __restrict__ mx_u,
    ushort_t* __restrict__ simbuf) {
    int bi, bj;
    tile_map(blockIdx.x, bi, bj);
    const int tid = threadIdx.x, wave = tid >> 6, lane = tid & 63;
    const int l15 = lane & 15, l4 = lane >> 4;
    const int row0 = bi * 64;
    const int col0 = bj * 256 + wave * 64;

    floatx4 acc[4][4];
#pragma unroll
    for (int m = 0; m < 4; m++)
#pragma unroll
        for (int n = 0; n < 4; n++) acc[m][n] = (floatx4){0.f, 0.f, 0.f, 0.f};

    const ushort_t* Abase = Tbf + (size_t)(row0 + l15) * DIM + l4 * 8;
    const ushort_t* Bbase = Tbf + (size_t)(col0 + l15) * DIM + l4 * 8;

#pragma unroll
    for (int t = 0; t < NSTEP; t++) {
        short8 a[4], b[4];
#pragma unroll
        for (int m = 0; m < 4; m++)
            a[m] = *reinterpret_cast<const short8*>(Abase + (size_t)m * 16 * DIM + t * 32);
#pragma unroll
        for (int n = 0; n < 4; n++)
            b[n] = *reinterpret_cast<const short8*>(Bbase + (size_t)n * 16 * DIM + t * 32);
#pragma unroll
        for (int m = 0; m < 4; m++)
#pragma unroll
            for (int n = 0; n < 4; n++)
                acc[m][n] = __builtin_amdgcn_mfma_f32_16x16x32_bf16(a[m], b[n], acc[m][n], 0, 0, 0);
    }

    // per-row min/max (fp32-exact); row = row0 + m*16 + l4*4 + reg, col = col0 + n*16 + l15
#pragma unroll
    for (int m = 0; m < 4; m++) {
#pragma unroll
        for (int reg = 0; reg < 4; reg++) {
            float vmin = acc[m][0][reg], vmax = acc[m][0][reg];
#pragma unroll
            for (int n = 1; n < 4; n++) {
                vmin = fminf(vmin, acc[m][n][reg]);
                vmax = fmaxf(vmax, acc[m][n][reg]);
            }
#pragma unroll
            for (int s = 1; s < 16; s <<= 1) {
                vmin = fminf(vmin, __shfl_xor(vmin, s));
                vmax = fmaxf(vmax, __shfl_xor(vmax, s));
            }
            if (l15 == 0) {
                int row_g = row0 + m * 16 + l4 * 4 + reg;
                atomicMin(&mn_u[row_g], fmap(vmin));
                atomicMax(&mx_u[row_g], fmap(vmax));
            }
        }
    }

    // packed bf16 sim store, fully coalesced: for fixed chunk c, 64 lanes write
    // 2 KB contiguous. element idx within lane = m*16 + n*4 + reg.
    const int wtid = bi * 64 + bj * 4 + wave;          // 64x64 wave-tile id
    ushort_t* sp = simbuf + (size_t)wtid * 4096;
#pragma unroll
    for (int c = 0; c < 8; c++) {
        int m = c >> 1, n0 = (c & 1) * 2;
        ushort8 o;
        o[0] = f2bf(acc[m][n0][0]);     o[1] = f2bf(acc[m][n0][1]);
        o[2] = f2bf(acc[m][n0][2]);     o[3] = f2bf(acc[m][n0][3]);
        o[4] = f2bf(acc[m][n0 + 1][0]); o[5] = f2bf(acc[m][n0 + 1][1]);
        o[6] = f2bf(acc[m][n0 + 1][2]); o[7] = f2bf(acc[m][n0 + 1][3]);
        *reinterpret_cast<ushort8*>(sp + c * 512 + lane * 8) = o;
    }
}

// ---------- kernel 2.5: per-row params {1/inorm, 1/tnorm, mn, 1/(mx-mn+eps)} ----------
__global__ __launch_bounds__(256) void params_kernel(
    const float* __restrict__ img_norm, const float* __restrict__ txt_norm,
    const unsigned* __restrict__ mn_u, const unsigned* __restrict__ mx_u,
    float4* __restrict__ params) {
    int i = blockIdx.x * 256 + threadIdx.x;
    float mn = funmap(mn_u[i]), mx = funmap(mx_u[i]);
    params[i] = make_float4(1.0f / img_norm[i], 1.0f / txt_norm[i],
                            mn, 1.0f / (mx - mn + EPS_W));
}

// ---------- kernel 3: D = I.T^T, LDS-free + loss epilogue ----------
__global__ __launch_bounds__(256, 4) void phase2_kernel(
    const ushort_t* __restrict__ Ibf, const ushort_t* __restrict__ Tbf,
    const float4* __restrict__ params, const int* __restrict__ instr,
    const ushort_t* __restrict__ simbuf, float* __restrict__ out) {
    int bi, bj;
    tile_map(blockIdx.x, bi, bj);
    const int tid = threadIdx.x, wave = tid >> 6, lane = tid & 63;
    const int l15 = lane & 15, l4 = lane >> 4;
    const int row0 = bi * 64;
    const int col0 = bj * 256 + wave * 64;

    floatx4 acc[4][4];
#pragma unroll
    for (int m = 0; m < 4; m++)
#pragma unroll
        for (int n = 0; n < 4; n++) acc[m][n] = (floatx4){0.f, 0.f, 0.f, 0.f};

    const ushort_t* Abase = Ibf + (size_t)(row0 + l15) * DIM + l4 * 8;
    const ushort_t* Bbase = Tbf + (size_t)(col0 + l15) * DIM + l4 * 8;

#pragma unroll
    for (int t = 0; t < NSTEP; t++) {
        short8 a[4], b[4];
#pragma unroll
        for (int m = 0; m < 4; m++)
            a[m] = *reinterpret_cast<const short8*>(Abase + (size_t)m * 16 * DIM + t * 32);
#pragma unroll
        for (int n = 0; n < 4; n++)
            b[n] = *reinterpret_cast<const short8*>(Bbase + (size_t)n * 16 * DIM + t * 32);
#pragma unroll
        for (int m = 0; m < 4; m++)
#pragma unroll
            for (int n = 0; n < 4; n++)
                acc[m][n] = __builtin_amdgcn_mfma_f32_16x16x32_bf16(a[m], b[n], acc[m][n], 0, 0, 0);
    }

    // epilogue: per-pair loss; sim readback (L2/L3-resident) + precomputed params
    const int wtid = bi * 64 + bj * 4 + wave;
    const ushort_t* sp = simbuf + (size_t)wtid * 4096;
    float rtn4[4]; int ic4[4];
#pragma unroll
    for (int n = 0; n < 4; n++) {
        int col_g = col0 + n * 16 + l15;
        rtn4[n] = params[col_g].y;
        ic4[n] = instr[col_g];
    }
    float lsum = 0.f;
#pragma unroll
    for (int m = 0; m < 4; m++) {
        ushort8 s0 = *reinterpret_cast<const ushort8*>(sp + (m * 2 + 0) * 512 + lane * 8);
        ushort8 s1 = *reinterpret_cast<const ushort8*>(sp + (m * 2 + 1) * 512 + lane * 8);
        int rb = row0 + m * 16 + l4 * 4;
#pragma unroll
        for (int reg = 0; reg < 4; reg++) {
            int row_g = rb + reg;
            float4 pp = params[row_g];        // {rinr, rtn, mn, winv}
            int   ir  = instr[row_g];
#pragma unroll
            for (int n = 0; n < 4; n++) {
                int col_g = col0 + n * 16 + l15;
                float simv = (n < 2) ? bf2f(s0[(n & 1) * 4 + reg])
                                     : bf2f(s1[(n & 1) * 4 + reg]);
                float cosv = acc[m][n][reg] * (pp.x * rtn4[n]);
                float w = (simv - pp.z) * pp.w;
                bool aligned = (ir == ic4[n]) || (row_g == col_g);
                lsum += aligned ? (1.0f - cosv) : fmaxf(0.0f, cosv - w);
            }
        }
    }
#pragma unroll
    for (int s = 1; s < 64; s <<= 1) lsum += __shfl_xor(lsum, s);
    if (lane == 0)
        atomicAdd(out, lsum * (1.0f / ((float)NROWS * (float)NROWS)));
}

// ---------- launch ----------
extern "C" void kernel_launch(void* const* d_in, const int* in_sizes, int n_in,
                              void* d_out, int out_size, void* d_ws, size_t ws_size,
                              hipStream_t stream) {
    const float* img = (const float*)d_in[0];
    const float* txt = (const float*)d_in[1];
    const int* instr = (const int*)d_in[2];
    float* out = (float*)d_out;

    char* ws = (char*)d_ws;
    ushort_t* Tbf = (ushort_t*)ws;                                  // 4 MB
    ushort_t* Ibf = (ushort_t*)(ws + (size_t)NROWS * DIM * 2);      // 4 MB
    float* inorm = (float*)(ws + (size_t)NROWS * DIM * 4);          // 16 KB
    float* tnorm = inorm + NROWS;                                   // 16 KB
    unsigned* mn_u = (unsigned*)(tnorm + NROWS);                    // 16 KB
    unsigned* mx_u = mn_u + NROWS;                                  // 16 KB
    float4* params = (float4*)(mx_u + NROWS);                       // 64 KB
    ushort_t* simbuf = (ushort_t*)(params + NROWS);                 // 32 MB

    hipMemsetAsync(d_out, 0, sizeof(float), stream);
    prep_kernel<<<NROWS / 4, 256, 0, stream>>>(img, txt, Ibf, Tbf,
                                               inorm, tnorm, mn_u, mx_u);
    phase1_kernel<<<1024, 256, 0, stream>>>(Tbf, mn_u, mx_u, simbuf);
    params_kernel<<<NROWS / 256, 256, 0, stream>>>(inorm, tnorm, mn_u, mx_u, params);
    phase2_kernel<<<1024, 256, 0, stream>>>(Ibf, Tbf, params, instr, simbuf, out);
}

// Round 9
// 117.203 us; speedup vs baseline: 1.6887x; 1.6887x over previous
//
#include <hip/hip_runtime.h>
#include <stdint.h>

#define NROWS 4096
#define DIM   512
#define EPS_W   1e-6f
#define NT    (NROWS / 128)        // 32 tiles per dim

typedef unsigned short ushort_t;
typedef __attribute__((ext_vector_type(8))) short   short8;
typedef __attribute__((ext_vector_type(8))) unsigned short ushort8;
typedef __attribute__((ext_vector_type(4))) float   floatx4;

// ---------- helpers ----------
__device__ inline ushort_t f2bf(float x) {            // RNE float->bf16
    unsigned u = __float_as_uint(x);
    unsigned r = (u + 0x7FFFu + ((u >> 16) & 1u)) >> 16;
    return (ushort_t)r;
}
__device__ inline float bf2f(ushort_t u) {
    return __uint_as_float(((unsigned)u) << 16);
}
__device__ inline unsigned fmap(float f) {
    unsigned u = __float_as_uint(f);
    return (u & 0x80000000u) ? ~u : (u | 0x80000000u);
}
__device__ inline float funmap(unsigned u) {
    return __uint_as_float((u & 0x80000000u) ? (u & 0x7fffffffu) : ~u);
}

__device__ inline void gload_lds16(const void* g, void* l) {
    auto* gp = reinterpret_cast<const __attribute__((address_space(1))) unsigned int*>(
        reinterpret_cast<uintptr_t>(g));
    auto* lp = reinterpret_cast<__attribute__((address_space(3))) unsigned int*>(
        reinterpret_cast<uintptr_t>(l));
    __builtin_amdgcn_global_load_lds(gp, lp, 16, 0, 0);
}

// R1-verified 128x64 staging (0 bank conflicts). LDS[r][c_phys] holds logical
// chunk c_phys ^ (r&7) (chunk = 16B = 8 bf16).
__device__ inline void stage_tile(const ushort_t* __restrict__ gbase,
                                  ushort_t* lds, int wave, int lane) {
#pragma unroll
    for (int q = 0; q < 4; q++) {
        int row0 = wave * 32 + q * 8;
        int lrow = row0 + (lane >> 3);
        int src_chunk = (lane & 7) ^ (lane >> 3);
        const ushort_t* g = gbase + (size_t)lrow * DIM + src_chunk * 8;
        gload_lds16(g, lds + row0 * 64);
    }
}
__device__ inline short8 read_frag(const ushort_t* tile, int frag_row, int kk, int lane) {
    int r = frag_row * 16 + (lane & 15);
    int c = (kk * 4 + (lane >> 4)) ^ (lane & 7);
    return *reinterpret_cast<const short8*>(tile + r * 64 + c * 8);
}

// ---------- kernel 1: convert (raw T + normalized I,T) + init ----------
__global__ __launch_bounds__(256) void prep_kernel(
    const float* __restrict__ img, const float* __restrict__ txt,
    ushort_t* __restrict__ Inrm, ushort_t* __restrict__ Traw,
    ushort_t* __restrict__ Tnrm,
    unsigned* __restrict__ mn_u, unsigned* __restrict__ mx_u) {
    const int wave = threadIdx.x >> 6, lane = threadIdx.x & 63;
    const int row = blockIdx.x * 4 + wave;
    const int col0 = lane * 8;
    {
        const float4* p = reinterpret_cast<const float4*>(img + (size_t)row * DIM + col0);
        float4 a = p[0], b = p[1];
        float ss = a.x*a.x + a.y*a.y + a.z*a.z + a.w*a.w
                 + b.x*b.x + b.y*b.y + b.z*b.z + b.w*b.w;
#pragma unroll
        for (int s = 1; s < 64; s <<= 1) ss += __shfl_xor(ss, s);
        float rin = rsqrtf(ss);                       // |I| ~ 22.6, never near 0
        ushort8 o;
        o[0]=f2bf(a.x*rin); o[1]=f2bf(a.y*rin); o[2]=f2bf(a.z*rin); o[3]=f2bf(a.w*rin);
        o[4]=f2bf(b.x*rin); o[5]=f2bf(b.y*rin); o[6]=f2bf(b.z*rin); o[7]=f2bf(b.w*rin);
        *reinterpret_cast<ushort8*>(Inrm + (size_t)row * DIM + col0) = o;
    }
    {
        const float4* p = reinterpret_cast<const float4*>(txt + (size_t)row * DIM + col0);
        float4 a = p[0], b = p[1];
        float ss = a.x*a.x + a.y*a.y + a.z*a.z + a.w*a.w
                 + b.x*b.x + b.y*b.y + b.z*b.z + b.w*b.w;
#pragma unroll
        for (int s = 1; s < 64; s <<= 1) ss += __shfl_xor(ss, s);
        float rtn = rsqrtf(ss);
        ushort8 r8, n8;
        r8[0]=f2bf(a.x); r8[1]=f2bf(a.y); r8[2]=f2bf(a.z); r8[3]=f2bf(a.w);
        r8[4]=f2bf(b.x); r8[5]=f2bf(b.y); r8[6]=f2bf(b.z); r8[7]=f2bf(b.w);
        n8[0]=f2bf(a.x*rtn); n8[1]=f2bf(a.y*rtn); n8[2]=f2bf(a.z*rtn); n8[3]=f2bf(a.w*rtn);
        n8[4]=f2bf(b.x*rtn); n8[5]=f2bf(b.y*rtn); n8[6]=f2bf(b.z*rtn); n8[7]=f2bf(b.w*rtn);
        *reinterpret_cast<ushort8*>(Traw + (size_t)row * DIM + col0) = r8;
        *reinterpret_cast<ushort8*>(Tnrm + (size_t)row * DIM + col0) = n8;
    }
    if (lane == 0) { mn_u[row] = 0xFFFFFFFFu; mx_u[row] = 0u; }
}

// ---------- kernel 2: fused S/D GEMM (R1-exact 128^2 loop) ----------
// even bid -> S = Traw.Traw^T (minmax atomics + packed bf16 sim)
// odd  bid -> D = Inrm.Tnrm^T = cos   (packed bf16 cos)
// Packed chunk-major layout: buf[wtid*4096 + c*512 + lane*8 .. +7],
// wtid = (ti*NT+tj)*4 + wave; in-lane element idx = m*16 + n*4 + reg,
// chunk c = m*2 + (n>>1), e = (n&1)*4 + reg.
__global__ __launch_bounds__(256) void gemm_kernel(
    const ushort_t* __restrict__ Traw, const ushort_t* __restrict__ Inrm,
    const ushort_t* __restrict__ Tnrm,
    unsigned* __restrict__ mn_u, unsigned* __restrict__ mx_u,
    ushort_t* __restrict__ simbuf, ushort_t* __restrict__ dotbuf, int sOnly) {
    __shared__ __align__(16) ushort_t Ta[128 * 64];
    __shared__ __align__(16) ushort_t Tb[128 * 64];
    const int bid = blockIdx.x;
    const int type = sOnly ? 0 : (bid & 1);
    const int b2 = sOnly ? bid : (bid >> 1);
    const int ti = b2 >> 5, tj = b2 & 31;
    const int wave = threadIdx.x >> 6, lane = threadIdx.x & 63;
    const int wr = wave >> 1, wc = wave & 1;
    const ushort_t* gA = (type ? Inrm : Traw) + (size_t)(ti * 128) * DIM;
    const ushort_t* gB = (type ? Tnrm : Traw) + (size_t)(tj * 128) * DIM;

    floatx4 acc[4][4];
#pragma unroll
    for (int m = 0; m < 4; m++)
#pragma unroll
        for (int n = 0; n < 4; n++) acc[m][n] = (floatx4){0.f, 0.f, 0.f, 0.f};

    for (int k0 = 0; k0 < DIM; k0 += 64) {
        __syncthreads();
        stage_tile(gA + k0, Ta, wave, lane);
        stage_tile(gB + k0, Tb, wave, lane);
        __syncthreads();
#pragma unroll
        for (int kk = 0; kk < 2; kk++) {
            short8 a[4], b[4];
#pragma unroll
            for (int m = 0; m < 4; m++) a[m] = read_frag(Ta, wr * 4 + m, kk, lane);
#pragma unroll
            for (int n = 0; n < 4; n++) b[n] = read_frag(Tb, wc * 4 + n, kk, lane);
#pragma unroll
            for (int m = 0; m < 4; m++)
#pragma unroll
                for (int n = 0; n < 4; n++)
                    acc[m][n] = __builtin_amdgcn_mfma_f32_16x16x32_bf16(a[m], b[n], acc[m][n], 0, 0, 0);
        }
    }

    ushort_t* sp = (type ? dotbuf : simbuf)
                 + ((size_t)((ti * NT + tj) * 4 + wave)) * 4096;

    if (type == 0) {
        // per-row min/max (fp32-exact)
#pragma unroll
        for (int m = 0; m < 4; m++) {
#pragma unroll
            for (int reg = 0; reg < 4; reg++) {
                float vmin = acc[m][0][reg], vmax = acc[m][0][reg];
#pragma unroll
                for (int n = 1; n < 4; n++) {
                    vmin = fminf(vmin, acc[m][n][reg]);
                    vmax = fmaxf(vmax, acc[m][n][reg]);
                }
#pragma unroll
                for (int s = 1; s < 16; s <<= 1) {
                    vmin = fminf(vmin, __shfl_xor(vmin, s));
                    vmax = fmaxf(vmax, __shfl_xor(vmax, s));
                }
                if ((lane & 15) == 0) {
                    int row_g = ti * 128 + wr * 64 + m * 16 + (lane >> 4) * 4 + reg;
                    atomicMin(&mn_u[row_g], fmap(vmin));
                    atomicMax(&mx_u[row_g], fmap(vmax));
                }
            }
        }
    }
    // packed bf16 store, chunk-major (64 lanes x 16B contiguous per chunk)
#pragma unroll
    for (int c = 0; c < 8; c++) {
        int m = c >> 1, n0 = (c & 1) * 2;
        ushort8 o;
        o[0] = f2bf(acc[m][n0][0]);     o[1] = f2bf(acc[m][n0][1]);
        o[2] = f2bf(acc[m][n0][2]);     o[3] = f2bf(acc[m][n0][3]);
        o[4] = f2bf(acc[m][n0 + 1][0]); o[5] = f2bf(acc[m][n0 + 1][1]);
        o[6] = f2bf(acc[m][n0 + 1][2]); o[7] = f2bf(acc[m][n0 + 1][3]);
        *reinterpret_cast<ushort8*>(sp + c * 512 + lane * 8) = o;
    }
}

// ---------- kernel 3: per-row params {mn, 1/(mx-mn+eps)} ----------
__global__ __launch_bounds__(256) void params_kernel(
    const unsigned* __restrict__ mn_u, const unsigned* __restrict__ mx_u,
    float2* __restrict__ params2) {
    int i = blockIdx.x * 256 + threadIdx.x;
    float mn = funmap(mn_u[i]), mx = funmap(mx_u[i]);
    params2[i] = make_float2(mn, 1.0f / (mx - mn + EPS_W));
}

// ---------- kernel 4: streaming loss ----------
// 2048 blocks x 256 thr x 4 slots = 2,097,152 ushort8-slots = all 16.7M pairs.
__global__ __launch_bounds__(256) void loss_kernel(
    const ushort_t* __restrict__ simbuf, const ushort_t* __restrict__ dotbuf,
    const float2* __restrict__ params2, const int* __restrict__ instr,
    float* __restrict__ out) {
    __shared__ float red[4];
    const int t = blockIdx.x * 256 + threadIdx.x;
    float lsum = 0.f;
#pragma unroll
    for (int k = 0; k < 4; k++) {
        int s = t + k * 524288;
        ushort8 sv = *reinterpret_cast<const ushort8*>(simbuf + (size_t)s * 8);
        ushort8 dv = *reinterpret_cast<const ushort8*>(dotbuf + (size_t)s * 8);
        int wtid = s >> 9, r = s & 511;
        int c = r >> 6, ln = r & 63;
        int wave = wtid & 3, tj = (wtid >> 2) & 31, ti = wtid >> 7;
        int m = c >> 1, n0 = (c & 1) * 2;
        int rb = ti * 128 + (wave >> 1) * 64 + m * 16 + (ln >> 4) * 4;  // %4 == 0
        int cb = tj * 128 + (wave & 1) * 64 + (ln & 15);
        float4 pA = *reinterpret_cast<const float4*>(params2 + rb);      // mn0,w0,mn1,w1
        float4 pB = *reinterpret_cast<const float4*>(params2 + rb + 2);  // mn2,w2,mn3,w3
        int4  ir4 = *reinterpret_cast<const int4*>(instr + rb);
        int ic0 = instr[cb + n0 * 16];
        int ic1 = instr[cb + n0 * 16 + 16];
#pragma unroll
        for (int e = 0; e < 8; e++) {
            const int reg = e & 3, hn = e >> 2;
            float mn, wv; int ir;
            if (reg == 0)      { mn = pA.x; wv = pA.y; ir = ir4.x; }
            else if (reg == 1) { mn = pA.z; wv = pA.w; ir = ir4.y; }
            else if (reg == 2) { mn = pB.x; wv = pB.y; ir = ir4.z; }
            else               { mn = pB.z; wv = pB.w; ir = ir4.w; }
            int ic = hn ? ic1 : ic0;
            int row = rb + reg, col = cb + (n0 + hn) * 16;
            float cosv = bf2f(dv[e]);
            float w = (bf2f(sv[e]) - mn) * wv;
            bool aligned = (ir == ic) || (row == col);
            lsum += aligned ? (1.0f - cosv) : fmaxf(0.0f, cosv - w);
        }
    }
#pragma unroll
    for (int s = 1; s < 64; s <<= 1) lsum += __shfl_xor(lsum, s);
    const int wave = threadIdx.x >> 6, lane = threadIdx.x & 63;
    if (lane == 0) red[wave] = lsum;
    __syncthreads();
    if (threadIdx.x == 0) {
        float v = red[0] + red[1] + red[2] + red[3];
        atomicAdd(out, v * (1.0f / ((float)NROWS * (float)NROWS)));
    }
}

// ---------- fallback: D-GEMM with fused loss epilogue (ws too small) ----------
__global__ __launch_bounds__(256) void dloss_kernel(
    const ushort_t* __restrict__ Inrm, const ushort_t* __restrict__ Tnrm,
    const float2* __restrict__ params2, const int* __restrict__ instr,
    const ushort_t* __restrict__ simbuf, float* __restrict__ out) {
    __shared__ __align__(16) ushort_t Ta[128 * 64];
    __shared__ __align__(16) ushort_t Tb[128 * 64];
    const int b2 = blockIdx.x;
    const int ti = b2 >> 5, tj = b2 & 31;
    const int wave = threadIdx.x >> 6, lane = threadIdx.x & 63;
    const int wr = wave >> 1, wc = wave & 1;
    const ushort_t* gA = Inrm + (size_t)(ti * 128) * DIM;
    const ushort_t* gB = Tnrm + (size_t)(tj * 128) * DIM;

    floatx4 acc[4][4];
#pragma unroll
    for (int m = 0; m < 4; m++)
#pragma unroll
        for (int n = 0; n < 4; n++) acc[m][n] = (floatx4){0.f, 0.f, 0.f, 0.f};

    for (int k0 = 0; k0 < DIM; k0 += 64) {
        __syncthreads();
        stage_tile(gA + k0, Ta, wave, lane);
        stage_tile(gB + k0, Tb, wave, lane);
        __syncthreads();
#pragma unroll
        for (int kk = 0; kk < 2; kk++) {
            short8 a[4], b[4];
#pragma unroll
            for (int m = 0; m < 4; m++) a[m] = read_frag(Ta, wr * 4 + m, kk, lane);
#pragma unroll
            for (int n = 0; n < 4; n++) b[n] = read_frag(Tb, wc * 4 + n, kk, lane);
#pragma unroll
            for (int m = 0; m < 4; m++)
#pragma unroll
                for (int n = 0; n < 4; n++)
                    acc[m][n] = __builtin_amdgcn_mfma_f32_16x16x32_bf16(a[m], b[n], acc[m][n], 0, 0, 0);
        }
    }

    const ushort_t* sp = simbuf + ((size_t)((ti * NT + tj) * 4 + wave)) * 4096;
    const int rbase0 = ti * 128 + wr * 64;
    const int cbase0 = tj * 128 + wc * 64;
    int ic4[4];
#pragma unroll
    for (int n = 0; n < 4; n++) ic4[n] = instr[cbase0 + n * 16 + (lane & 15)];
    float lsum = 0.f;
#pragma unroll
    for (int m = 0; m < 4; m++) {
        ushort8 s0 = *reinterpret_cast<const ushort8*>(sp + (m * 2 + 0) * 512 + lane * 8);
        ushort8 s1 = *reinterpret_cast<const ushort8*>(sp + (m * 2 + 1) * 512 + lane * 8);
        int rb = rbase0 + m * 16 + (lane >> 4) * 4;
#pragma unroll
        for (int reg = 0; reg < 4; reg++) {
            int row_g = rb + reg;
            float2 pp = params2[row_g];
            int   ir  = instr[row_g];
#pragma unroll
            for (int n = 0; n < 4; n++) {
                int col_g = cbase0 + n * 16 + (lane & 15);
                float simv = (n < 2) ? bf2f(s0[(n & 1) * 4 + reg])
                                     : bf2f(s1[(n & 1) * 4 + reg]);
                float cosv = acc[m][n][reg];
                float w = (simv - pp.x) * pp.y;
                bool aligned = (ir == ic4[n]) || (row_g == col_g);
                lsum += aligned ? (1.0f - cosv) : fmaxf(0.0f, cosv - w);
            }
        }
    }
#pragma unroll
    for (int s = 1; s < 64; s <<= 1) lsum += __shfl_xor(lsum, s);
    if (lane == 0)
        atomicAdd(out, lsum * (1.0f / ((float)NROWS * (float)NROWS)));
}

// ---------- launch ----------
extern "C" void kernel_launch(void* const* d_in, const int* in_sizes, int n_in,
                              void* d_out, int out_size, void* d_ws, size_t ws_size,
                              hipStream_t stream) {
    const float* img = (const float*)d_in[0];
    const float* txt = (const float*)d_in[1];
    const int* instr = (const int*)d_in[2];
    float* out = (float*)d_out;

    char* ws = (char*)d_ws;
    const size_t MAT = (size_t)NROWS * DIM * 2;                     // 4 MB
    ushort_t* Traw = (ushort_t*)ws;
    ushort_t* Inrm = (ushort_t*)(ws + MAT);
    ushort_t* Tnrm = (ushort_t*)(ws + 2 * MAT);
    unsigned* mn_u = (unsigned*)(ws + 3 * MAT);                     // 16 KB
    unsigned* mx_u = mn_u + NROWS;                                  // 16 KB
    float2* params2 = (float2*)(mx_u + NROWS);                      // 32 KB
    ushort_t* simbuf = (ushort_t*)(params2 + NROWS);                // 32 MB
    ushort_t* dotbuf = simbuf + (size_t)NROWS * NROWS;              // 32 MB
    const size_t need = 3 * MAT + (size_t)NROWS * 16
                      + 2 * (size_t)NROWS * NROWS * 2;

    hipMemsetAsync(d_out, 0, sizeof(float), stream);
    prep_kernel<<<NROWS / 4, 256, 0, stream>>>(img, txt, Inrm, Traw, Tnrm, mn_u, mx_u);
    if (ws_size >= need) {
        gemm_kernel<<<2 * NT * NT, 256, 0, stream>>>(Traw, Inrm, Tnrm,
                                                     mn_u, mx_u, simbuf, dotbuf, 0);
        params_kernel<<<NROWS / 256, 256, 0, stream>>>(mn_u, mx_u, params2);
        loss_kernel<<<2048, 256, 0, stream>>>(simbuf, dotbuf, params2, instr, out);
    } else {
        gemm_kernel<<<NT * NT, 256, 0, stream>>>(Traw, Inrm, Tnrm,
                                                 mn_u, mx_u, simbuf, simbuf, 1);
        params_kernel<<<NROWS / 256, 256, 0, stream>>>(mn_u, mx_u, params2);
        dloss_kernel<<<NT * NT, 256, 0, stream>>>(Inrm, Tnrm, params2, instr, simbuf, out);
    }
}